// Round 17
// baseline (1583.927 us; speedup 1.0000x reference)
//
#include <hip/hip_runtime.h>
#include <math.h>

#define Bn 128
#define Tn 256
#define Fn 36
#define Hn 128
#define BTFn (Bn*Tn*Fn)
#define TF 9216

// ws float offsets
#define INVD_OFF 0
#define LOSS_OFF 102656
#define IMP_OFF  103040

// ---- LDS word offsets (7736 words = 30.2 KB -> 2 blocks/CU) ----
#define OFF_WHIST  0      // [q<64][f<36] f16-pairs        : 2304
#define OFF_WF     2304   // [q<18][g<36] diag-zeroed      : 648
#define OFF_WWC    2952   // [q<36][g<36]                  : 1296
#define OFF_WDHT   4248   // [q<18][u<128]                 : 2304
#define OFF_IN     6552   // f32 [par<2][w<5][f<36]        : 360
#define OFF_DP     6912   // [par<2][20]                   : 40
#define OFF_MP     6952   // [par<2][20]                   : 40
#define OFF_GXP    6992   // [par<2][20]                   : 40
#define OFF_XCP    7032   // 20
#define OFF_CCP    7052   // 20
#define OFF_ALPHA  7072   // f32 36
#define OFF_HP     7108   // 64 f16-pairs
#define OFF_INVD   7172   // f32 256
#define OFF_BH     7428   // 36
#define OFF_BF     7464   // 36
#define OFF_BWC    7500   // 36
#define OFF_BDH    7536   // f32 128
#define OFF_WDXD   7664   // f32 36
#define OFF_BDX    7700   // f32 36
#define SMEM_WORDS 7736

typedef _Float16 h2_t __attribute__((ext_vector_type(2)));

__device__ __forceinline__ unsigned int bcu(float x) { return __builtin_bit_cast(unsigned int, x); }
__device__ __forceinline__ unsigned int pkh(float a, float b) {
    return __builtin_bit_cast(unsigned int, __builtin_amdgcn_cvt_pkrtz(a, b));
}
__device__ __forceinline__ float dot2(unsigned int a, unsigned int b, float c) {
    return __builtin_amdgcn_fdot2(__builtin_bit_cast(h2_t, a), __builtin_bit_cast(h2_t, b), c, false);
}
__device__ __forceinline__ float sigmoid_f(float x) {
    return __builtin_amdgcn_rcpf(1.f + __expf(-x));
}
__device__ __forceinline__ float tanh_f(float x) {
    return fmaf(2.f, __builtin_amdgcn_rcpf(1.f + __expf(-2.f * x)), -1.f);
}

// ---------------- prep: inv-denom per t ----------------
__global__ void prep_kernel(const float* __restrict__ data,
                            float* __restrict__ ws) {
    int t = blockIdx.x;
    int tid = threadIdx.x;
    __shared__ float red[256];
    float s = 0.f;
    for (int idx = tid; idx < Bn * Fn; idx += 256) {
        int b = idx / Fn, f = idx - b * Fn;
        s += data[((size_t)(b * 24 + 1) * Tn + t) * Fn + f];
    }
    red[tid] = s;
    __syncthreads();
    for (int off = 128; off > 0; off >>= 1) {
        if (tid < off) red[tid] += red[tid + off];
        __syncthreads();
    }
    if (tid == 0) ws[INVD_OFF + t] = 1.f / (red[0] + 1e-5f);
}

// 18 packed dots from LDS base (%4==0) against wi[woff..+17]
#define DOT18(acc, base, woff) do {                                    \
    const unsigned int* _p = &smem[(base)];                            \
    float _a = 0.f, _b = 0.f;                                          \
    float4 _v0 = *(const float4*)_p;                                   \
    _a = dot2(bcu(_v0.x), wi[(woff) + 0], _a);                         \
    _b = dot2(bcu(_v0.y), wi[(woff) + 1], _b);                         \
    _a = dot2(bcu(_v0.z), wi[(woff) + 2], _a);                         \
    _b = dot2(bcu(_v0.w), wi[(woff) + 3], _b);                         \
    float4 _v1 = *(const float4*)(_p + 4);                             \
    _a = dot2(bcu(_v1.x), wi[(woff) + 4], _a);                         \
    _b = dot2(bcu(_v1.y), wi[(woff) + 5], _b);                         \
    _a = dot2(bcu(_v1.z), wi[(woff) + 6], _a);                         \
    _b = dot2(bcu(_v1.w), wi[(woff) + 7], _b);                         \
    float4 _v2 = *(const float4*)(_p + 8);                             \
    _a = dot2(bcu(_v2.x), wi[(woff) + 8], _a);                         \
    _b = dot2(bcu(_v2.y), wi[(woff) + 9], _b);                         \
    _a = dot2(bcu(_v2.z), wi[(woff) + 10], _a);                        \
    _b = dot2(bcu(_v2.w), wi[(woff) + 11], _b);                        \
    float4 _v3 = *(const float4*)(_p + 12);                            \
    _a = dot2(bcu(_v3.x), wi[(woff) + 12], _a);                        \
    _b = dot2(bcu(_v3.y), wi[(woff) + 13], _b);                        \
    _a = dot2(bcu(_v3.z), wi[(woff) + 14], _a);                        \
    _b = dot2(bcu(_v3.w), wi[(woff) + 15], _b);                        \
    float2 _v4 = *(const float2*)(_p + 16);                            \
    _a = dot2(bcu(_v4.x), wi[(woff) + 16], _a);                        \
    _b = dot2(bcu(_v4.y), wi[(woff) + 17], _b);                        \
    acc += _a + _b;                                                    \
} while (0)

// loader staging of one float2 (2 features); P = parity
#define STAGE(v, P) do {                                                          \
    if (lw == 0) {                                                                \
        *(float2*)&smf[OFF_IN + (P) * 180 + 2 * lu] = (v);                        \
        smem[OFF_MP + (P) * 20 + lu] = pkh((v).x, (v).y);                         \
    } else if (lw == 1) {                                                         \
        smem[OFF_DP + (P) * 20 + lu] = pkh((v).x, (v).y);                         \
        float2 _wd = *(const float2*)&smf[OFF_WDXD + 2 * lu];                     \
        float2 _bd = *(const float2*)&smf[OFF_BDX + 2 * lu];                      \
        float _g0 = __expf(-fmaxf(fmaf((v).x, _wd.x, _bd.x), 0.f));               \
        float _g1 = __expf(-fmaxf(fmaf((v).y, _wd.y, _bd.y), 0.f));               \
        smem[OFF_GXP + (P) * 20 + lu] = pkh(_g0, _g1);                            \
    } else {                                                                      \
        *(float2*)&smf[OFF_IN + (P) * 180 + lw * 36 + 2 * lu] = (v);              \
    }                                                                             \
} while (0)

// ---------------- main: 384 blocks x 512 threads, 1 chain/block, 2 barriers/step ----------------
__global__ __launch_bounds__(512) void rits_main(
    const float* __restrict__ data,
    const float* __restrict__ W_dh, const float* __restrict__ b_dh,
    const float* __restrict__ W_dx, const float* __restrict__ b_dx,
    const float* __restrict__ W_hist, const float* __restrict__ b_hist,
    const float* __restrict__ W_feat, const float* __restrict__ b_feat,
    const float* __restrict__ W_wc, const float* __restrict__ b_wc,
    const float* __restrict__ W_ih, const float* __restrict__ W_hh,
    const float* __restrict__ b_ih, const float* __restrict__ b_hh,
    const float* __restrict__ W_comb,
    float* __restrict__ ws) {

    extern __shared__ unsigned int smem[];
    float* smf = (float*)smem;

    const int tid = threadIdx.x;
    const int lane = tid & 63;
    const int wv = tid >> 6;
    // in-wave gate mapping: unit u = wv*16 + (lane&15), gate = lane>>4
    const int unit = wv * 16 + (lane & 15);
    const int row_j = unit + 128 * (lane >> 4);
    const int chain = blockIdx.x;
    const int b = chain / 3, k = chain - 3 * b;

    // ---- one-time LDS staging (r14 layouts: b32 weight reads, zero conflicts) ----
    for (int i = tid; i < 64 * Fn; i += 512) {
        int q = i / Fn, f = i - q * Fn;
        float2 wvv = *(const float2*)&W_hist[f * Hn + 2 * q];
        smem[OFF_WHIST + i] = pkh(wvv.x, wvv.y);
    }
    for (int i = tid; i < 18 * Fn; i += 512) {
        int q = i / Fn, g = i - q * Fn;
        float2 wvv = *(const float2*)&W_feat[g * Fn + 2 * q];
        float w0 = (2 * q     == g) ? 0.f : wvv.x;
        float w1 = (2 * q + 1 == g) ? 0.f : wvv.y;
        smem[OFF_WF + i] = pkh(w0, w1);
    }
    for (int i = tid; i < 36 * Fn; i += 512) {
        int q = i / Fn, g = i - q * Fn;
        int col = (q < 18) ? 2 * q : Fn + 2 * (q - 18);
        float2 wvv = *(const float2*)&W_wc[g * 2 * Fn + col];
        smem[OFF_WWC + i] = pkh(wvv.x, wvv.y);
    }
    for (int i = tid; i < 18 * 128; i += 512) {
        int q = i >> 7, u = i & 127;
        float2 wvv = *(const float2*)&W_dh[u * Fn + 2 * q];
        smem[OFF_WDHT + i] = pkh(wvv.x, wvv.y);
    }
    if (tid < Fn) {
        smf[OFF_BH + tid]   = b_hist[tid];
        smf[OFF_BF + tid]   = b_feat[tid];
        smf[OFF_BWC + tid]  = b_wc[tid];
        smf[OFF_WDXD + tid] = W_dx[tid * Fn + tid];
        smf[OFF_BDX + tid]  = b_dx[tid];
    }
    if (tid < Hn) smf[OFF_BDH + tid] = b_dh[tid];
    for (int i = tid; i < Tn; i += 512) smf[OFF_INVD + i] = ws[INVD_OFF + i];
    if (tid < 64) smem[OFF_HP + tid] = 0;

    // ---- per-thread gate-row registers (row_j): W_hh row (64 u32) + W_ih row (36 u32) ----
    unsigned int wh[64];
    #pragma unroll
    for (int q = 0; q < 64; ++q) {
        float2 wvv = *(const float2*)&W_hh[row_j * Hn + 2 * q];
        wh[q] = pkh(wvv.x, wvv.y);
    }
    unsigned int wi[36];
    #pragma unroll
    for (int q = 0; q < 36; ++q) {
        float2 wvv = *(const float2*)&W_ih[row_j * 2 * Fn + 2 * q];
        wi[q] = pkh(wvv.x, wvv.y);
    }
    const float bias_j = b_ih[row_j] + b_hh[row_j];

    // ---- loader role: tid in [64,154), 90 threads x float2 over 5 rows ----
    const float* ldsrc = nullptr; int lw = 0, lu = 0;
    if (tid >= 64 && tid < 154) {
        int idx = tid - 64;
        lw = idx / 18; lu = idx - 18 * lw;
        int row = (lw == 0) ? 1 : (lw == 1) ? 2 : (3 + 3 * k + (lw - 2));
        ldsrc = data + (size_t)(b * 24 + row) * TF + 2 * lu;
    }
    // ---- feature role: tid<36 (wave 0) ----
    float* impp = ws + IMP_OFF + (size_t)(k * Bn + b) * TF;

    float creg = 0.f, loss_acc = 0.f, gm = 0.f;
    __syncthreads();

    // ---- prologue: load t=0..3, stage t=0 (parity 0); then alpha(0)+gm(0) ----
    float2 cur1 = {0,0}, cur2 = {0,0}, cur3 = {0,0};
    float2 nxt0 = {0,0}, nxt1 = {0,0}, nxt2 = {0,0}, nxt3 = {0,0};
    if (ldsrc) {
        float2 c0 = *(const float2*)(ldsrc);
        cur1 = *(const float2*)(ldsrc + Fn);
        cur2 = *(const float2*)(ldsrc + 2 * Fn);
        cur3 = *(const float2*)(ldsrc + 3 * Fn);
        STAGE(c0, 0);
    }
    __syncthreads();
    if (tid >= 144 && tid < 180) {
        int f = tid - 144;
        float a0 = smf[OFF_BWC + f], a1 = 0.f;
        #pragma unroll
        for (int q = 0; q < 18; ++q) {
            a0 = dot2(smem[OFF_GXP + q], smem[OFF_WWC + q * Fn + f], a0);
            a1 = dot2(smem[OFF_MP + q],  smem[OFF_WWC + (18 + q) * Fn + f], a1);
        }
        smf[OFF_ALPHA + f] = a0 + a1;
    }
    DOT18(gm, OFF_MP, 18);       // gm(0), parity 0
    __syncthreads();

    for (int t8 = 0; t8 < Tn; t8 += 4) {
        float iv0 = 0.f, iv1 = 0.f, iv2 = 0.f, iv3 = 0.f;
        #pragma unroll
        for (int s = 0; s < 4; ++s) {
            const int t = t8 + s;
            const int par = s & 1, parn = par ^ 1;   // t8 mult of 4 -> t parity == s parity

            // ======== P_A: hh-dot (all) | features (tid<36) | stage t+1 + refill (loaders) ========
            if (s == 0 && ldsrc) {
                nxt0 = *(const float2*)(ldsrc + (size_t)(t8 + 4) * Fn);
                nxt1 = *(const float2*)(ldsrc + (size_t)(t8 + 5) * Fn);
                nxt2 = *(const float2*)(ldsrc + (size_t)(t8 + 6) * Fn);
                nxt3 = *(const float2*)(ldsrc + (size_t)(t8 + 7) * Fn);
            }
            float gacc;
            {
                float g0 = 0.f, g1 = 0.f, g2 = 0.f, g3 = 0.f;
                #pragma unroll
                for (int q = 0; q < 64; q += 4) {
                    float4 hp = *(const float4*)&smem[OFF_HP + q];
                    g0 = dot2(bcu(hp.x), wh[q],     g0);
                    g1 = dot2(bcu(hp.y), wh[q + 1], g1);
                    g2 = dot2(bcu(hp.z), wh[q + 2], g2);
                    g3 = dot2(bcu(hp.w), wh[q + 3], g3);
                }
                gacc = (g0 + g1) + (g2 + g3);
            }
            if (tid < Fn) {
                const int inb = OFF_IN + par * 180;
                float m  = smf[inb + tid];
                float rt = smf[inb + 72 + tid];
                float a0 = 0.f, a1 = 0.f, a2 = 0.f, a3 = 0.f;
                #pragma unroll
                for (int q = 0; q < 64; q += 4) {
                    unsigned int h0 = smem[OFF_HP + q];
                    unsigned int h1 = smem[OFF_HP + q + 1];
                    unsigned int h2 = smem[OFF_HP + q + 2];
                    unsigned int h3 = smem[OFF_HP + q + 3];
                    a0 = dot2(h0, smem[OFF_WHIST + q * Fn + tid], a0);
                    a1 = dot2(h1, smem[OFF_WHIST + (q + 1) * Fn + tid], a1);
                    a2 = dot2(h2, smem[OFF_WHIST + (q + 2) * Fn + tid], a2);
                    a3 = dot2(h3, smem[OFF_WHIST + (q + 3) * Fn + tid], a3);
                }
                float xh = (a0 + a1) + (a2 + a3) + smf[OFF_BH + tid];
                float xc = m * rt + (1.f - m) * xh;
                float xcn = __shfl_xor(xc, 1);
                if (!(tid & 1)) smem[OFF_XCP + (tid >> 1)] = pkh(xc, xcn);
                // zh: same-wave LDS round-trip (wave-ordered, no barrier)
                float z0 = 0.f, z1 = 0.f;
                #pragma unroll
                for (int q = 0; q < 18; q += 2) {
                    z0 = dot2(smem[OFF_XCP + q], smem[OFF_WF + q * Fn + tid], z0);
                    z1 = dot2(smem[OFF_XCP + q + 1], smem[OFF_WF + (q + 1) * Fn + tid], z1);
                }
                float zh = z0 + z1 + smf[OFF_BF + tid];
                float al = smf[OFF_ALPHA + tid];
                float chv = al * zh + (1.f - al) * xh;
                float cc = m * rt + (1.f - m) * chv;
                loss_acc = fmaf((fabsf(rt - xh) + fabsf(rt - zh) + fabsf(rt - chv)) * m,
                                smf[OFF_INVD + t], loss_acc);
                float ccn = __shfl_xor(cc, 1);
                if (!(tid & 1)) smem[OFF_CCP + (tid >> 1)] = pkh(cc, ccn);
                float iv = cc + smf[inb + 144 + tid] + smf[inb + 108 + tid];
                if (s == 0) iv0 = iv; else if (s == 1) iv1 = iv;
                else if (s == 2) iv2 = iv; else iv3 = iv;
            }
            if (ldsrc) {   // stage inputs for t+1 into parity parn
                if (s == 0) STAGE(cur1, parn);
                else if (s == 1) STAGE(cur2, parn);
                else if (s == 2) STAGE(cur3, parn);
                else STAGE(nxt0, parn);
            }
            __syncthreads();   // B2

            // ======== P_B: gate finalize + in-wave gather + LSTM+decay (lane<16) | alpha(t+1) | gm(t+1) ========
            {
                float gate = gacc + gm + bias_j;
                DOT18(gate, OFF_CCP, 0);
                const int base = lane & 15;
                float fg = __shfl(gate, base + 16, 64);
                float gg = __shfl(gate, base + 32, 64);
                float og = __shfl(gate, base + 48, 64);
                if (lane < 16) {
                    creg = sigmoid_f(fg) * creg + sigmoid_f(gate) * tanh_f(gg);
                    float hn_ = sigmoid_f(og) * tanh_f(creg);
                    // decay(t+1) from DP[parn]
                    float g0 = smf[OFF_BDH + unit], g1 = 0.f;
                    #pragma unroll
                    for (int q = 0; q < 18; q += 2) {
                        g0 = dot2(smem[OFF_DP + parn * 20 + q], smem[OFF_WDHT + q * 128 + unit], g0);
                        g1 = dot2(smem[OFF_DP + parn * 20 + q + 1], smem[OFF_WDHT + (q + 1) * 128 + unit], g1);
                    }
                    float hreg = hn_ * __expf(-fmaxf(g0 + g1, 0.f));
                    float hn2 = __shfl_xor(hreg, 1);
                    if (!(lane & 1)) smem[OFF_HP + (unit >> 1)] = pkh(hreg, hn2);
                } else if (tid >= 144 && tid < 180) {
                    int f = tid - 144;
                    float a0 = smf[OFF_BWC + f], a1 = 0.f;
                    #pragma unroll
                    for (int q = 0; q < 18; ++q) {
                        a0 = dot2(smem[OFF_GXP + parn * 20 + q], smem[OFF_WWC + q * Fn + f], a0);
                        a1 = dot2(smem[OFF_MP + parn * 20 + q], smem[OFF_WWC + (18 + q) * Fn + f], a1);
                    }
                    smf[OFF_ALPHA + f] = a0 + a1;
                }
            }
            gm = 0.f;
            DOT18(gm, OFF_MP + parn * 20, 18);   // m(t+1), staged in P_A
            __syncthreads();   // B1

            // imp flush once per 4 steps; stores drain under next group's phases
            if (s == 3 && tid < Fn) {
                impp[(size_t)t8 * Fn + tid]       = iv0;
                impp[(size_t)(t8 + 1) * Fn + tid] = iv1;
                impp[(size_t)(t8 + 2) * Fn + tid] = iv2;
                impp[(size_t)(t8 + 3) * Fn + tid] = iv3;
            }
        }
        if (ldsrc) { cur1 = nxt1; cur2 = nxt2; cur3 = nxt3; }
    }

    // ---- loss partial (fixed order -> deterministic) ----
    __syncthreads();
    if (tid < Fn) smf[OFF_IN + tid] = loss_acc;
    __syncthreads();
    if (tid == 0) {
        float s = 0.f;
        for (int i = 0; i < Fn; ++i) s += smf[OFF_IN + i];
        float w0 = W_comb[0], w1 = W_comb[1], w2 = W_comb[2];
        float mx = fmaxf(w0, fmaxf(w1, w2));
        float e0 = expf(w0 - mx), e1 = expf(w1 - mx), e2 = expf(w2 - mx);
        float wkk = ((k == 0) ? e0 : (k == 1) ? e1 : e2) / (e0 + e1 + e2);
        ws[LOSS_OFF + chain] = s * wkk;
    }
}

// ---------------- k-reduction of imputations ----------------
__global__ void impute_reduce(const float* __restrict__ ws,
                              const float* __restrict__ W_comb,
                              float* __restrict__ out) {
    int idx = blockIdx.x * 256 + threadIdx.x;
    float w0 = W_comb[0], w1 = W_comb[1], w2 = W_comb[2];
    float mx = fmaxf(w0, fmaxf(w1, w2));
    float e0 = expf(w0 - mx), e1 = expf(w1 - mx), e2 = expf(w2 - mx);
    float inv = 1.f / (e0 + e1 + e2);
    const float* imp = ws + IMP_OFF;
    out[1 + idx] = (e0 * imp[idx] + e1 * imp[BTFn + idx] + e2 * imp[2 * BTFn + idx]) * inv;
}

// ---------------- final loss (384 per-chain partials) ----------------
__global__ void loss_final(const float* __restrict__ ws,
                           const float* __restrict__ W_comb,
                           float* __restrict__ out) {
    int tid = threadIdx.x;
    __shared__ float red[512];
    const float* lp = ws + LOSS_OFF;
    red[tid] = (tid < 384) ? lp[tid] : 0.f;
    __syncthreads();
    for (int off = 256; off > 0; off >>= 1) {
        if (tid < off) red[tid] += red[tid + off];
        __syncthreads();
    }
    if (tid == 0) {
        float w0 = W_comb[0], w1 = W_comb[1], w2 = W_comb[2];
        float mx = fmaxf(w0, fmaxf(w1, w2));
        float e0 = expf(w0 - mx), e1 = expf(w1 - mx), e2 = expf(w2 - mx);
        float inv = 1.f / (e0 + e1 + e2);
        float wk0 = e0 * inv, wk1 = e1 * inv, wk2 = e2 * inv;
        float reg = 0.1f * (wk0 * (1.f / 24.f) + wk1 * (1.f / 168.f) + wk2 * (1.f / 720.f));
        out[0] = red[0] + (float)Tn * reg;
    }
}

extern "C" void kernel_launch(void* const* d_in, const int* in_sizes, int n_in,
                              void* d_out, int out_size, void* d_ws, size_t ws_size,
                              hipStream_t stream) {
    const float* data   = (const float*)d_in[0];
    const float* W_dh   = (const float*)d_in[1];
    const float* b_dh   = (const float*)d_in[2];
    const float* W_dx   = (const float*)d_in[3];
    const float* b_dx   = (const float*)d_in[4];
    const float* W_hist = (const float*)d_in[5];
    const float* b_hist = (const float*)d_in[6];
    const float* W_feat = (const float*)d_in[7];
    const float* b_feat = (const float*)d_in[8];
    const float* W_wc   = (const float*)d_in[9];
    const float* b_wc   = (const float*)d_in[10];
    const float* W_ih   = (const float*)d_in[11];
    const float* W_hh   = (const float*)d_in[12];
    const float* b_ih   = (const float*)d_in[13];
    const float* b_hh   = (const float*)d_in[14];
    const float* W_comb = (const float*)d_in[15];
    float* ws = (float*)d_ws;
    float* out = (float*)d_out;

    hipLaunchKernelGGL(prep_kernel, dim3(Tn), dim3(256), 0, stream, data, ws);
    hipLaunchKernelGGL(rits_main, dim3(Bn * 3), dim3(512), SMEM_WORDS * 4, stream,
                       data, W_dh, b_dh, W_dx, b_dx, W_hist, b_hist,
                       W_feat, b_feat, W_wc, b_wc, W_ih, W_hh, b_ih, b_hh, W_comb, ws);
    hipLaunchKernelGGL(impute_reduce, dim3(BTFn / 256), dim3(256), 0, stream, ws, W_comb, out);
    hipLaunchKernelGGL(loss_final, dim3(1), dim3(512), 0, stream, ws, W_comb, out);
}

// Round 18
// 1015.598 us; speedup vs baseline: 1.5596x; 1.5596x over previous
//
#include <hip/hip_runtime.h>
#include <math.h>

#define Bn 128
#define Tn 256
#define Fn 36
#define Hn 128
#define G4 512
#define BTFn (Bn*Tn*Fn)
#define TF 9216

// ws float offsets
#define INVD_OFF 0
#define LOSS_OFF 102656
#define IMP_OFF  103040

// ---- LDS word offsets (total 8028 words = 31.4 KB -> 2 blocks/CU) ----
#define OFF_WHIST  0      // [q<64][f<36] f16-pairs        : 2304
#define OFF_WF     2304   // [q<18][g<36] diag-zeroed      : 648
#define OFF_WWC    2952   // [q<36][g<36]                  : 1296
#define OFF_WDHT   4248   // [q<18][u<128]                 : 2304
#define OFF_IN     6552   // f32 [w<5][f<36] m,-,rt,tr,se  : 180
#define OFF_DP     6732   // 20
#define OFF_MP     6752   // [par<2][20]                   : 40
#define OFF_GXP    6792   // 20
#define OFF_XCP    6812   // 20
#define OFF_CCP    6832   // 20
#define OFF_ALPHA  6852   // f32 36
#define OFF_HP     6888   // 64 f16-pairs
#define OFF_GF     6952   // f32 512
#define OFF_INVD   7464   // f32 256
#define OFF_BH     7720   // 36
#define OFF_BF     7756   // 36
#define OFF_BWC    7792   // 36
#define OFF_BDH    7828   // f32 128
#define OFF_WDXD   7956   // f32 36
#define OFF_BDX    7992   // f32 36
#define SMEM_WORDS 8028

typedef _Float16 h2_t __attribute__((ext_vector_type(2)));

__device__ __forceinline__ unsigned int bcu(float x) { return __builtin_bit_cast(unsigned int, x); }
__device__ __forceinline__ unsigned int pkh(float a, float b) {
    return __builtin_bit_cast(unsigned int, __builtin_amdgcn_cvt_pkrtz(a, b));
}
__device__ __forceinline__ float dot2(unsigned int a, unsigned int b, float c) {
    return __builtin_amdgcn_fdot2(__builtin_bit_cast(h2_t, a), __builtin_bit_cast(h2_t, b), c, false);
}
__device__ __forceinline__ float sigmoid_f(float x) {
    return __builtin_amdgcn_rcpf(1.f + __expf(-x));
}
__device__ __forceinline__ float tanh_f(float x) {
    return fmaf(2.f, __builtin_amdgcn_rcpf(1.f + __expf(-2.f * x)), -1.f);
}

// ---------------- prep: inv-denom per t ----------------
__global__ void prep_kernel(const float* __restrict__ data,
                            float* __restrict__ ws) {
    int t = blockIdx.x;
    int tid = threadIdx.x;
    __shared__ float red[256];
    float s = 0.f;
    for (int idx = tid; idx < Bn * Fn; idx += 256) {
        int b = idx / Fn, f = idx - b * Fn;
        s += data[((size_t)(b * 24 + 1) * Tn + t) * Fn + f];
    }
    red[tid] = s;
    __syncthreads();
    for (int off = 128; off > 0; off >>= 1) {
        if (tid < off) red[tid] += red[tid + off];
        __syncthreads();
    }
    if (tid == 0) ws[INVD_OFF + t] = 1.f / (red[0] + 1e-5f);
}

// 18 packed dots from LDS base (%4==0) against wi[woff..+17]
#define DOT18(acc, base, woff) do {                                    \
    const unsigned int* _p = &smem[(base)];                            \
    float _a = 0.f, _b = 0.f;                                          \
    float4 _v0 = *(const float4*)_p;                                   \
    _a = dot2(bcu(_v0.x), wi[(woff) + 0], _a);                         \
    _b = dot2(bcu(_v0.y), wi[(woff) + 1], _b);                         \
    _a = dot2(bcu(_v0.z), wi[(woff) + 2], _a);                         \
    _b = dot2(bcu(_v0.w), wi[(woff) + 3], _b);                         \
    float4 _v1 = *(const float4*)(_p + 4);                             \
    _a = dot2(bcu(_v1.x), wi[(woff) + 4], _a);                         \
    _b = dot2(bcu(_v1.y), wi[(woff) + 5], _b);                         \
    _a = dot2(bcu(_v1.z), wi[(woff) + 6], _a);                         \
    _b = dot2(bcu(_v1.w), wi[(woff) + 7], _b);                         \
    float4 _v2 = *(const float4*)(_p + 8);                             \
    _a = dot2(bcu(_v2.x), wi[(woff) + 8], _a);                         \
    _b = dot2(bcu(_v2.y), wi[(woff) + 9], _b);                         \
    _a = dot2(bcu(_v2.z), wi[(woff) + 10], _a);                        \
    _b = dot2(bcu(_v2.w), wi[(woff) + 11], _b);                        \
    float4 _v3 = *(const float4*)(_p + 12);                            \
    _a = dot2(bcu(_v3.x), wi[(woff) + 12], _a);                        \
    _b = dot2(bcu(_v3.y), wi[(woff) + 13], _b);                        \
    _a = dot2(bcu(_v3.z), wi[(woff) + 14], _a);                        \
    _b = dot2(bcu(_v3.w), wi[(woff) + 15], _b);                        \
    float2 _v4 = *(const float2*)(_p + 16);                            \
    _a = dot2(bcu(_v4.x), wi[(woff) + 16], _a);                        \
    _b = dot2(bcu(_v4.y), wi[(woff) + 17], _b);                        \
    acc += _a + _b;                                                    \
} while (0)

// loader staging of one float2 (2 features); P = MP parity for m
#define STAGE(v, P) do {                                                          \
    if (lw == 0) {                                                                \
        *(float2*)&smf[OFF_IN + 2 * lu] = (v);                                    \
        smem[OFF_MP + (P) * 20 + lu] = pkh((v).x, (v).y);                         \
    } else if (lw == 1) {                                                         \
        smem[OFF_DP + lu] = pkh((v).x, (v).y);                                    \
        float2 _wd = *(const float2*)&smf[OFF_WDXD + 2 * lu];                     \
        float2 _bd = *(const float2*)&smf[OFF_BDX + 2 * lu];                      \
        float _g0 = __expf(-fmaxf(fmaf((v).x, _wd.x, _bd.x), 0.f));               \
        float _g1 = __expf(-fmaxf(fmaf((v).y, _wd.y, _bd.y), 0.f));               \
        smem[OFF_GXP + lu] = pkh(_g0, _g1);                                       \
    } else {                                                                      \
        *(float2*)&smf[OFF_IN + lw * 36 + 2 * lu] = (v);                          \
    }                                                                             \
} while (0)

// ---------------- main: 384 blocks x 512 threads, 1 chain/block, 2 blocks/CU ----------------
__global__ __launch_bounds__(512) void rits_main(
    const float* __restrict__ data,
    const float* __restrict__ W_dh, const float* __restrict__ b_dh,
    const float* __restrict__ W_dx, const float* __restrict__ b_dx,
    const float* __restrict__ W_hist, const float* __restrict__ b_hist,
    const float* __restrict__ W_feat, const float* __restrict__ b_feat,
    const float* __restrict__ W_wc, const float* __restrict__ b_wc,
    const float* __restrict__ W_ih, const float* __restrict__ W_hh,
    const float* __restrict__ b_ih, const float* __restrict__ b_hh,
    const float* __restrict__ W_comb,
    float* __restrict__ ws) {

    extern __shared__ unsigned int smem[];
    float* smf = (float*)smem;

    const int tid = threadIdx.x;
    const int chain = blockIdx.x;
    const int b = chain / 3, k = chain - 3 * b;

    // ---- one-time LDS staging (small matrices only) ----
    for (int i = tid; i < 64 * Fn; i += 512) {
        int q = i / Fn, f = i - q * Fn;
        float2 wv = *(const float2*)&W_hist[f * Hn + 2 * q];
        smem[OFF_WHIST + i] = pkh(wv.x, wv.y);
    }
    for (int i = tid; i < 18 * Fn; i += 512) {
        int q = i / Fn, g = i - q * Fn;
        float2 wv = *(const float2*)&W_feat[g * Fn + 2 * q];
        float w0 = (2 * q     == g) ? 0.f : wv.x;
        float w1 = (2 * q + 1 == g) ? 0.f : wv.y;
        smem[OFF_WF + i] = pkh(w0, w1);
    }
    for (int i = tid; i < 36 * Fn; i += 512) {
        int q = i / Fn, g = i - q * Fn;
        int col = (q < 18) ? 2 * q : Fn + 2 * (q - 18);
        float2 wv = *(const float2*)&W_wc[g * 2 * Fn + col];
        smem[OFF_WWC + i] = pkh(wv.x, wv.y);
    }
    for (int i = tid; i < 18 * 128; i += 512) {
        int q = i >> 7, u = i & 127;
        float2 wv = *(const float2*)&W_dh[u * Fn + 2 * q];
        smem[OFF_WDHT + i] = pkh(wv.x, wv.y);
    }
    if (tid < Fn) {
        smf[OFF_BH + tid]   = b_hist[tid];
        smf[OFF_BF + tid]   = b_feat[tid];
        smf[OFF_BWC + tid]  = b_wc[tid];
        smf[OFF_WDXD + tid] = W_dx[tid * Fn + tid];
        smf[OFF_BDX + tid]  = b_dx[tid];
    }
    if (tid < Hn) smf[OFF_BDH + tid] = b_dh[tid];
    for (int i = tid; i < Tn; i += 512) smf[OFF_INVD + i] = ws[INVD_OFF + i];
    if (tid < 64) smem[OFF_HP + tid] = 0;

    // ---- per-thread gate-row registers: W_hh row (64 u32) + W_ih row (36 u32) ----
    unsigned int wh[64];
    #pragma unroll
    for (int q = 0; q < 64; ++q) {
        float2 wv = *(const float2*)&W_hh[tid * Hn + 2 * q];
        wh[q] = pkh(wv.x, wv.y);
    }
    unsigned int wi[36];
    #pragma unroll
    for (int q = 0; q < 36; ++q) {
        float2 wv = *(const float2*)&W_ih[tid * 2 * Fn + 2 * q];
        wi[q] = pkh(wv.x, wv.y);
    }
    const float bias_j = b_ih[tid] + b_hh[tid];

    // ---- loader role: tid in [64,154), 90 threads x float2 over 5 rows ----
    const float* ldsrc = nullptr; int lw = 0, lu = 0;
    if (tid >= 64 && tid < 154) {
        int idx = tid - 64;
        lw = idx / 18; lu = idx - 18 * lw;
        int row = (lw == 0) ? 1 : (lw == 1) ? 2 : (3 + 3 * k + (lw - 2));
        ldsrc = data + (size_t)(b * 24 + row) * TF + 2 * lu;
    }
    // ---- feature role: tid<36 ----
    float* impp = ws + IMP_OFF + (size_t)(k * Bn + b) * TF;

    float creg = 0.f, hreg = 0.f, loss_acc = 0.f, gm = 0.f;
    __syncthreads();

    // ---- prologue: load t=0..3, stage t=0 (MP parity 0); then alpha(0)+gm(0) ----
    float2 cur1 = {0,0}, cur2 = {0,0}, cur3 = {0,0};
    float2 nxt0 = {0,0}, nxt1 = {0,0}, nxt2 = {0,0}, nxt3 = {0,0};
    if (ldsrc) {
        float2 c0 = *(const float2*)(ldsrc);
        cur1 = *(const float2*)(ldsrc + Fn);
        cur2 = *(const float2*)(ldsrc + 2 * Fn);
        cur3 = *(const float2*)(ldsrc + 3 * Fn);
        STAGE(c0, 0);
    }
    __syncthreads();
    if (tid >= 128 && tid < 164) {
        int f = tid - 128;
        float a0 = smf[OFF_BWC + f], a1 = 0.f;
        #pragma unroll
        for (int q = 0; q < 18; ++q) {
            a0 = dot2(smem[OFF_GXP + q], smem[OFF_WWC + q * Fn + f], a0);
            a1 = dot2(smem[OFF_MP + q],  smem[OFF_WWC + (18 + q) * Fn + f], a1);
        }
        smf[OFF_ALPHA + f] = a0 + a1;
    }
    DOT18(gm, OFF_MP, 18);       // gm(0), MP parity 0
    __syncthreads();

    for (int t8 = 0; t8 < Tn; t8 += 4) {
        float iv0 = 0.f, iv1 = 0.f, iv2 = 0.f, iv3 = 0.f;
        #pragma unroll
        for (int s = 0; s < 4; ++s) {
            const int t = t8 + s;
            const int par = s & 1, parn = par ^ 1;   // t8 mult of 4 -> t parity == s parity

            // ======== P_A: hh-dot (all) | features (tid<36) | batched loads (s==0) ========
            if (s == 0 && ldsrc) {
                nxt0 = *(const float2*)(ldsrc + (size_t)(t8 + 4) * Fn);
                nxt1 = *(const float2*)(ldsrc + (size_t)(t8 + 5) * Fn);
                nxt2 = *(const float2*)(ldsrc + (size_t)(t8 + 6) * Fn);
                nxt3 = *(const float2*)(ldsrc + (size_t)(t8 + 7) * Fn);
            }
            float gacc;
            {
                float g0 = 0.f, g1 = 0.f, g2 = 0.f, g3 = 0.f;
                #pragma unroll
                for (int q = 0; q < 64; q += 4) {
                    float4 hp = *(const float4*)&smem[OFF_HP + q];
                    g0 = dot2(bcu(hp.x), wh[q],     g0);
                    g1 = dot2(bcu(hp.y), wh[q + 1], g1);
                    g2 = dot2(bcu(hp.z), wh[q + 2], g2);
                    g3 = dot2(bcu(hp.w), wh[q + 3], g3);
                }
                gacc = (g0 + g1) + (g2 + g3);
            }
            if (tid < Fn) {
                float m  = smf[OFF_IN + tid];
                float rt = smf[OFF_IN + 72 + tid];
                float a0 = 0.f, a1 = 0.f, a2 = 0.f, a3 = 0.f;
                #pragma unroll
                for (int q = 0; q < 64; q += 4) {
                    unsigned int h0 = smem[OFF_HP + q];
                    unsigned int h1 = smem[OFF_HP + q + 1];
                    unsigned int h2 = smem[OFF_HP + q + 2];
                    unsigned int h3 = smem[OFF_HP + q + 3];
                    a0 = dot2(h0, smem[OFF_WHIST + q * Fn + tid], a0);
                    a1 = dot2(h1, smem[OFF_WHIST + (q + 1) * Fn + tid], a1);
                    a2 = dot2(h2, smem[OFF_WHIST + (q + 2) * Fn + tid], a2);
                    a3 = dot2(h3, smem[OFF_WHIST + (q + 3) * Fn + tid], a3);
                }
                float xh = (a0 + a1) + (a2 + a3) + smf[OFF_BH + tid];
                float xc = m * rt + (1.f - m) * xh;
                float xcn = __shfl_xor(xc, 1);
                if (!(tid & 1)) smem[OFF_XCP + (tid >> 1)] = pkh(xc, xcn);
                // zh: same-wave LDS round-trip (wave-ordered, no barrier)
                float z0 = 0.f, z1 = 0.f;
                #pragma unroll
                for (int q = 0; q < 18; q += 2) {
                    z0 = dot2(smem[OFF_XCP + q], smem[OFF_WF + q * Fn + tid], z0);
                    z1 = dot2(smem[OFF_XCP + q + 1], smem[OFF_WF + (q + 1) * Fn + tid], z1);
                }
                float zh = z0 + z1 + smf[OFF_BF + tid];
                float al = smf[OFF_ALPHA + tid];
                float chv = al * zh + (1.f - al) * xh;
                float cc = m * rt + (1.f - m) * chv;
                loss_acc = fmaf((fabsf(rt - xh) + fabsf(rt - zh) + fabsf(rt - chv)) * m,
                                smf[OFF_INVD + t], loss_acc);
                float ccn = __shfl_xor(cc, 1);
                if (!(tid & 1)) smem[OFF_CCP + (tid >> 1)] = pkh(cc, ccn);
                float iv = cc + smf[OFF_IN + 144 + tid] + smf[OFF_IN + 108 + tid];
                if (s == 0) iv0 = iv; else if (s == 1) iv1 = iv;
                else if (s == 2) iv2 = iv; else iv3 = iv;
            }
            __syncthreads();   // B2

            // ======== P_B: gate finalize (cc-part only) | stage t+1 (loaders) ========
            {
                float gA = gacc + gm + bias_j;
                DOT18(gA, OFF_CCP, 0);
                smf[OFF_GF + tid] = gA;
            }
            if (ldsrc) {
                if (s == 0) STAGE(cur1, parn);
                else if (s == 1) STAGE(cur2, parn);
                else if (s == 2) STAGE(cur3, parn);
                else STAGE(nxt0, parn);
            }
            __syncthreads();   // B3

            // ======== P_C: LSTM+decay+hpack (tid<128) | alpha(t+1) (128..163) | gm(t+1) all ========
            if (tid < Hn) {
                float ig = smf[OFF_GF + tid];
                float fg = smf[OFF_GF + 128 + tid];
                float gg = smf[OFF_GF + 256 + tid];
                float og = smf[OFF_GF + 384 + tid];
                creg = sigmoid_f(fg) * creg + sigmoid_f(ig) * tanh_f(gg);
                float hn_ = sigmoid_f(og) * tanh_f(creg);
                float g0 = smf[OFF_BDH + tid], g1 = 0.f;
                #pragma unroll
                for (int q = 0; q < 18; q += 2) {
                    g0 = dot2(smem[OFF_DP + q], smem[OFF_WDHT + q * 128 + tid], g0);
                    g1 = dot2(smem[OFF_DP + q + 1], smem[OFF_WDHT + (q + 1) * 128 + tid], g1);
                }
                hreg = hn_ * __expf(-fmaxf(g0 + g1, 0.f));
                float hn2 = __shfl_xor(hreg, 1);
                if (!(tid & 1)) smem[OFF_HP + (tid >> 1)] = pkh(hreg, hn2);
            } else if (tid < 164) {
                int f = tid - 128;
                float a0 = smf[OFF_BWC + f], a1 = 0.f;
                #pragma unroll
                for (int q = 0; q < 18; ++q) {
                    a0 = dot2(smem[OFF_GXP + q], smem[OFF_WWC + q * Fn + f], a0);
                    a1 = dot2(smem[OFF_MP + parn * 20 + q], smem[OFF_WWC + (18 + q) * Fn + f], a1);
                }
                smf[OFF_ALPHA + f] = a0 + a1;
            }
            gm = 0.f;
            DOT18(gm, OFF_MP + parn * 20, 18);   // m(t+1), staged in P_B
            __syncthreads();   // B1

            // imp flush once per 4 steps; stores drain under next group's P_A->B2
            if (s == 3 && tid < Fn) {
                impp[(size_t)t8 * Fn + tid]       = iv0;
                impp[(size_t)(t8 + 1) * Fn + tid] = iv1;
                impp[(size_t)(t8 + 2) * Fn + tid] = iv2;
                impp[(size_t)(t8 + 3) * Fn + tid] = iv3;
            }
        }
        if (ldsrc) { cur1 = nxt1; cur2 = nxt2; cur3 = nxt3; }
    }

    // ---- loss partial (fixed order -> deterministic) ----
    if (tid < Fn) smf[OFF_GF + tid] = loss_acc;
    __syncthreads();
    if (tid == 0) {
        float s = 0.f;
        for (int i = 0; i < Fn; ++i) s += smf[OFF_GF + i];
        float w0 = W_comb[0], w1 = W_comb[1], w2 = W_comb[2];
        float mx = fmaxf(w0, fmaxf(w1, w2));
        float e0 = expf(w0 - mx), e1 = expf(w1 - mx), e2 = expf(w2 - mx);
        float wkk = ((k == 0) ? e0 : (k == 1) ? e1 : e2) / (e0 + e1 + e2);
        ws[LOSS_OFF + chain] = s * wkk;
    }
}

// ---------------- k-reduction of imputations ----------------
__global__ void impute_reduce(const float* __restrict__ ws,
                              const float* __restrict__ W_comb,
                              float* __restrict__ out) {
    int idx = blockIdx.x * 256 + threadIdx.x;
    float w0 = W_comb[0], w1 = W_comb[1], w2 = W_comb[2];
    float mx = fmaxf(w0, fmaxf(w1, w2));
    float e0 = expf(w0 - mx), e1 = expf(w1 - mx), e2 = expf(w2 - mx);
    float inv = 1.f / (e0 + e1 + e2);
    const float* imp = ws + IMP_OFF;
    out[1 + idx] = (e0 * imp[idx] + e1 * imp[BTFn + idx] + e2 * imp[2 * BTFn + idx]) * inv;
}

// ---------------- final loss (384 per-chain partials) ----------------
__global__ void loss_final(const float* __restrict__ ws,
                           const float* __restrict__ W_comb,
                           float* __restrict__ out) {
    int tid = threadIdx.x;
    __shared__ float red[512];
    const float* lp = ws + LOSS_OFF;
    red[tid] = (tid < 384) ? lp[tid] : 0.f;
    __syncthreads();
    for (int off = 256; off > 0; off >>= 1) {
        if (tid < off) red[tid] += red[tid + off];
        __syncthreads();
    }
    if (tid == 0) {
        float w0 = W_comb[0], w1 = W_comb[1], w2 = W_comb[2];
        float mx = fmaxf(w0, fmaxf(w1, w2));
        float e0 = expf(w0 - mx), e1 = expf(w1 - mx), e2 = expf(w2 - mx);
        float inv = 1.f / (e0 + e1 + e2);
        float wk0 = e0 * inv, wk1 = e1 * inv, wk2 = e2 * inv;
        float reg = 0.1f * (wk0 * (1.f / 24.f) + wk1 * (1.f / 168.f) + wk2 * (1.f / 720.f));
        out[0] = red[0] + (float)Tn * reg;
    }
}

extern "C" void kernel_launch(void* const* d_in, const int* in_sizes, int n_in,
                              void* d_out, int out_size, void* d_ws, size_t ws_size,
                              hipStream_t stream) {
    const float* data   = (const float*)d_in[0];
    const float* W_dh   = (const float*)d_in[1];
    const float* b_dh   = (const float*)d_in[2];
    const float* W_dx   = (const float*)d_in[3];
    const float* b_dx   = (const float*)d_in[4];
    const float* W_hist = (const float*)d_in[5];
    const float* b_hist = (const float*)d_in[6];
    const float* W_feat = (const float*)d_in[7];
    const float* b_feat = (const float*)d_in[8];
    const float* W_wc   = (const float*)d_in[9];
    const float* b_wc   = (const float*)d_in[10];
    const float* W_ih   = (const float*)d_in[11];
    const float* W_hh   = (const float*)d_in[12];
    const float* b_ih   = (const float*)d_in[13];
    const float* b_hh   = (const float*)d_in[14];
    const float* W_comb = (const float*)d_in[15];
    float* ws = (float*)d_ws;
    float* out = (float*)d_out;

    hipLaunchKernelGGL(prep_kernel, dim3(Tn), dim3(256), 0, stream, data, ws);
    hipLaunchKernelGGL(rits_main, dim3(Bn * 3), dim3(512), SMEM_WORDS * 4, stream,
                       data, W_dh, b_dh, W_dx, b_dx, W_hist, b_hist,
                       W_feat, b_feat, W_wc, b_wc, W_ih, W_hh, b_ih, b_hh, W_comb, ws);
    hipLaunchKernelGGL(impute_reduce, dim3(BTFn / 256), dim3(256), 0, stream, ws, W_comb, out);
    hipLaunchKernelGGL(loss_final, dim3(1), dim3(512), 0, stream, ws, W_comb, out);
}